// Round 1
// baseline (407.238 us; speedup 1.0000x reference)
//
#include <hip/hip_runtime.h>

// SIREN inference: N=2097152 points, fp32.
//   L0: 2->32 sine, L1..L4: 32->32 sine, L5: 32->16 sine, final: 16->3 + sigmoid
// sin(30*(x@W^T+b)). One thread per point; activations in VGPRs; weights read
// with wave-uniform indices -> scalar loads (s_load) + v_fmac_f32 with SGPR src.

#define OMEGA0 30.0f
#define INV2PI 0.15915494309189535f
#define SINSCALE (OMEGA0 * INV2PI)   // 30/(2*pi): pre-activation -> revolutions

// sin(2*pi*u): reduce to [0,1) then v_sin_f32 (revolution-domain HW sine).
__device__ __forceinline__ float sin_rev(float u) {
    u = u - floorf(u);
    return __builtin_amdgcn_sinf(u);
}

__device__ __forceinline__ float fast_sigmoid(float t) {
    // 1/(1+e^-t); e^-t = 2^(-t*log2e)
    float e = __builtin_amdgcn_exp2f(t * -1.4426950408889634f);
    return 1.0f / (1.0f + e);
}

__global__ __launch_bounds__(256) void siren_kernel(
    const float* __restrict__ coords,
    const float* __restrict__ w0, const float* __restrict__ b0,
    const float* __restrict__ w1, const float* __restrict__ b1,
    const float* __restrict__ w2, const float* __restrict__ b2,
    const float* __restrict__ w3, const float* __restrict__ b3,
    const float* __restrict__ w4, const float* __restrict__ b4,
    const float* __restrict__ w5, const float* __restrict__ b5,
    const float* __restrict__ wf, const float* __restrict__ bf,
    float* __restrict__ out, int n)
{
    int i = blockIdx.x * blockDim.x + threadIdx.x;
    if (i >= n) return;

    const float2 c = reinterpret_cast<const float2*>(coords)[i];

    float x[32];

    // ---- layer 0: 2 -> 32 ----
#pragma unroll
    for (int j = 0; j < 32; ++j) {
        float acc = fmaf(w0[2 * j + 0], c.x, fmaf(w0[2 * j + 1], c.y, b0[j]));
        x[j] = sin_rev(acc * SINSCALE);
    }

    // ---- layers 1..4: 32 -> 32 (looped to keep kernel inside I$) ----
#pragma unroll 1
    for (int l = 0; l < 4; ++l) {
        const float* __restrict__ W = (l == 0) ? w1 : (l == 1) ? w2 : (l == 2) ? w3 : w4;
        const float* __restrict__ B = (l == 0) ? b1 : (l == 1) ? b2 : (l == 2) ? b3 : b4;
        float y[32];
#pragma unroll
        for (int j = 0; j < 32; j += 4) {
            float a0 = B[j + 0];
            float a1 = B[j + 1];
            float a2 = B[j + 2];
            float a3 = B[j + 3];
#pragma unroll
            for (int k = 0; k < 32; ++k) {
                const float xv = x[k];
                a0 = fmaf(W[(j + 0) * 32 + k], xv, a0);
                a1 = fmaf(W[(j + 1) * 32 + k], xv, a1);
                a2 = fmaf(W[(j + 2) * 32 + k], xv, a2);
                a3 = fmaf(W[(j + 3) * 32 + k], xv, a3);
            }
            y[j + 0] = sin_rev(a0 * SINSCALE);
            y[j + 1] = sin_rev(a1 * SINSCALE);
            y[j + 2] = sin_rev(a2 * SINSCALE);
            y[j + 3] = sin_rev(a3 * SINSCALE);
        }
#pragma unroll
        for (int j = 0; j < 32; ++j) x[j] = y[j];
    }

    // ---- layer 5: 32 -> 16 sine ----
    float h[16];
#pragma unroll
    for (int j = 0; j < 16; j += 4) {
        float a0 = b5[j + 0];
        float a1 = b5[j + 1];
        float a2 = b5[j + 2];
        float a3 = b5[j + 3];
#pragma unroll
        for (int k = 0; k < 32; ++k) {
            const float xv = x[k];
            a0 = fmaf(w5[(j + 0) * 32 + k], xv, a0);
            a1 = fmaf(w5[(j + 1) * 32 + k], xv, a1);
            a2 = fmaf(w5[(j + 2) * 32 + k], xv, a2);
            a3 = fmaf(w5[(j + 3) * 32 + k], xv, a3);
        }
        h[j + 0] = sin_rev(a0 * SINSCALE);
        h[j + 1] = sin_rev(a1 * SINSCALE);
        h[j + 2] = sin_rev(a2 * SINSCALE);
        h[j + 3] = sin_rev(a3 * SINSCALE);
    }

    // ---- final: 16 -> 3 linear + sigmoid ----
    float o[3];
#pragma unroll
    for (int j = 0; j < 3; ++j) {
        float a = bf[j];
#pragma unroll
        for (int k = 0; k < 16; ++k) a = fmaf(wf[j * 16 + k], h[k], a);
        o[j] = fast_sigmoid(a);
    }

    out[3 * i + 0] = o[0];
    out[3 * i + 1] = o[1];
    out[3 * i + 2] = o[2];
}

extern "C" void kernel_launch(void* const* d_in, const int* in_sizes, int n_in,
                              void* d_out, int out_size, void* d_ws, size_t ws_size,
                              hipStream_t stream) {
    const float* coords = (const float*)d_in[0];
    const float* w0 = (const float*)d_in[1];
    const float* b0 = (const float*)d_in[2];
    const float* w1 = (const float*)d_in[3];
    const float* b1 = (const float*)d_in[4];
    const float* w2 = (const float*)d_in[5];
    const float* b2 = (const float*)d_in[6];
    const float* w3 = (const float*)d_in[7];
    const float* b3 = (const float*)d_in[8];
    const float* w4 = (const float*)d_in[9];
    const float* b4 = (const float*)d_in[10];
    const float* w5 = (const float*)d_in[11];
    const float* b5 = (const float*)d_in[12];
    const float* wf = (const float*)d_in[13];
    const float* bf = (const float*)d_in[14];
    float* out = (float*)d_out;

    const int n = in_sizes[0] / 2;
    dim3 block(256);
    dim3 grid((n + 255) / 256);
    siren_kernel<<<grid, block, 0, stream>>>(
        coords, w0, b0, w1, b1, w2, b2, w3, b3, w4, b4, w5, b5, wf, bf, out, n);
}

// Round 2
// 212.426 us; speedup vs baseline: 1.9171x; 1.9171x over previous
//
#include <hip/hip_runtime.h>
#include <hip/hip_bf16.h>

// SIREN via MFMA, bf16 hi/lo split (fp32-accurate to ~1e-4).
// Wave = 64 points. Layers 1..5 as v_mfma_f32_16x16x32_bf16:
//   D[16pt x 16feat] = A[16pt x 32k] * B[32k x 16feat], 3 MFMAs per tile (hh+hl+lh).
// Activations live in wave-private LDS: C-layout writes, A-layout ds_read_b128.
// Verified layouts (learn_hip): C/D col=lane&15,row=(lane>>4)*4+reg; A[m=lane&15][k=(lane>>4)*8+j].
// 30/(2pi) folded into weights+biases by prep kernel -> activation = fract + v_sin.

#define SINSCALE 4.774648292756860f   // 30/(2*pi)
#define RS 40                          // act row stride in ushorts (80 B -> 20-bank stride, 2-way = free)

typedef __attribute__((ext_vector_type(8))) short short8;
typedef __attribute__((ext_vector_type(4))) float f32x4;

__device__ __forceinline__ float sin_rev(float u) {
    u = u - floorf(u);                      // v_fract_f32
    return __builtin_amdgcn_sinf(u);        // v_sin_f32, revolutions
}

__device__ __forceinline__ float fast_sigmoid(float t) {
    float e = __builtin_amdgcn_exp2f(t * -1.4426950408889634f);
    return 1.0f / (1.0f + e);
}

union BFU { __hip_bfloat16 b; unsigned short u; };

__device__ __forceinline__ void bsplit(float v, unsigned short& h, unsigned short& l) {
    BFU x; x.b = __float2bfloat16(v);
    h = x.u;
    float fh = __uint_as_float(((unsigned)x.u) << 16);
    BFU y; y.b = __float2bfloat16(v - fh);
    l = y.u;
}

__device__ __forceinline__ float bf2f(short s) {
    return __uint_as_float(((unsigned)(unsigned short)s) << 16);
}

// ---- prep: convert w1..w5 (scaled by SINSCALE) into B-fragment-ordered bf16 hi/lo ----
// set s in [0,9): s=0..7 -> layer l=s>>1 (w1..w4), n-tile u=s&1; s=8 -> w5 (u=0).
// B frag: lane L holds B[k=(L>>4)*8+j][n=(L&15)+16u] = W[n][k]*SINSCALE, j=0..7.
__global__ void prep_kernel(const float* __restrict__ w1, const float* __restrict__ w2,
                            const float* __restrict__ w3, const float* __restrict__ w4,
                            const float* __restrict__ w5,
                            const float* __restrict__ b1, const float* __restrict__ b2,
                            const float* __restrict__ b3, const float* __restrict__ b4,
                            const float* __restrict__ b5,
                            unsigned short* __restrict__ frag_hi,
                            unsigned short* __restrict__ frag_lo,
                            float* __restrict__ bsc) {
    int lane = threadIdx.x;  // 64 threads
    const float* Ws[5] = {w1, w2, w3, w4, w5};
    for (int s = 0; s < 9; ++s) {
        const float* W = Ws[s >> 1];
        int u = s & 1;                       // s=8 -> u=0, W=w5
        int nrow = (lane & 15) + 16 * u;
        int k0 = (lane >> 4) * 8;
        for (int j = 0; j < 8; ++j) {
            float v = W[nrow * 32 + k0 + j] * SINSCALE;
            unsigned short h, l;
            bsplit(v, h, l);
            frag_hi[(s * 64 + lane) * 8 + j] = h;
            frag_lo[(s * 64 + lane) * 8 + j] = l;
        }
    }
    if (lane < 32) {
        bsc[0 * 32 + lane] = b1[lane] * SINSCALE;
        bsc[1 * 32 + lane] = b2[lane] * SINSCALE;
        bsc[2 * 32 + lane] = b3[lane] * SINSCALE;
        bsc[3 * 32 + lane] = b4[lane] * SINSCALE;
    }
    if (lane < 16) bsc[128 + lane] = b5[lane] * SINSCALE;
}

__global__ __launch_bounds__(256, 4) void siren_mfma(
    const float* __restrict__ coords,
    const float* __restrict__ w0, const float* __restrict__ b0,
    const unsigned short* __restrict__ frag_hi,
    const unsigned short* __restrict__ frag_lo,
    const float* __restrict__ bsc,
    const float* __restrict__ wf, const float* __restrict__ bfin,
    float* __restrict__ out, int n) {
    __shared__ __align__(16) unsigned short lds[4][2][64 * RS];  // 40960 B/block

    const int lane = (int)(threadIdx.x & 63);
    const int wv = (int)(threadIdx.x >> 6);
    unsigned short* AH = &lds[wv][0][0];
    unsigned short* AL = &lds[wv][1][0];

    const int pbase = blockIdx.x * 256 + wv * 64;
    const int pt = pbase + lane;
    const int ptc = min(pt, n - 1);

    // ---- L0: 2 -> 32, point-per-lane, writes act rows [lane][0..31] ----
    {
        const float2 c = reinterpret_cast<const float2*>(coords)[ptc];
#pragma unroll
        for (int j = 0; j < 32; ++j) {
            float a = fmaf(w0[2 * j], c.x, fmaf(w0[2 * j + 1], c.y, b0[j])) * SINSCALE;
            float s = sin_rev(a);
            unsigned short h, l;
            bsplit(s, h, l);
            AH[lane * RS + j] = h;
            AL[lane * RS + j] = l;
        }
    }

    const int q = lane >> 4;
    const int nl = lane & 15;
    const int aoff = nl * RS + q * 8;  // A-frag: row=nl(+16t), k0=8q -> 16B aligned

    const short8* FH = reinterpret_cast<const short8*>(frag_hi);
    const short8* FL = reinterpret_cast<const short8*>(frag_lo);

    // ---- middle layers 1..4: 32 -> 32 ----
#pragma unroll 1
    for (int l = 0; l < 4; ++l) {
        short8 Bh0 = FH[(l * 2 + 0) * 64 + lane];
        short8 Bh1 = FH[(l * 2 + 1) * 64 + lane];
        short8 Bl0 = FL[(l * 2 + 0) * 64 + lane];
        short8 Bl1 = FL[(l * 2 + 1) * 64 + lane];
        float bias0 = bsc[l * 32 + nl];
        float bias1 = bsc[l * 32 + nl + 16];

        f32x4 acc[4][2];
#pragma unroll
        for (int t = 0; t < 4; ++t) {
            short8 Ah = *reinterpret_cast<const short8*>(&AH[aoff + t * 16 * RS]);
            short8 Al = *reinterpret_cast<const short8*>(&AL[aoff + t * 16 * RS]);
            f32x4 a0 = {bias0, bias0, bias0, bias0};
            a0 = __builtin_amdgcn_mfma_f32_16x16x32_bf16(Ah, Bh0, a0, 0, 0, 0);
            a0 = __builtin_amdgcn_mfma_f32_16x16x32_bf16(Ah, Bl0, a0, 0, 0, 0);
            a0 = __builtin_amdgcn_mfma_f32_16x16x32_bf16(Al, Bh0, a0, 0, 0, 0);
            f32x4 a1 = {bias1, bias1, bias1, bias1};
            a1 = __builtin_amdgcn_mfma_f32_16x16x32_bf16(Ah, Bh1, a1, 0, 0, 0);
            a1 = __builtin_amdgcn_mfma_f32_16x16x32_bf16(Ah, Bl1, a1, 0, 0, 0);
            a1 = __builtin_amdgcn_mfma_f32_16x16x32_bf16(Al, Bh1, a1, 0, 0, 0);
            acc[t][0] = a0;
            acc[t][1] = a1;
        }
        // activation + write back (C layout: row=16t+4q+r, col=nl+16u)
#pragma unroll
        for (int t = 0; t < 4; ++t)
#pragma unroll
            for (int u = 0; u < 2; ++u)
#pragma unroll
                for (int r = 0; r < 4; ++r) {
                    float s = sin_rev(acc[t][u][r]);
                    unsigned short h, l2;
                    bsplit(s, h, l2);
                    const int m = 16 * t + 4 * q + r;
                    AH[m * RS + nl + 16 * u] = h;
                    AL[m * RS + nl + 16 * u] = l2;
                }
    }

    // ---- L5: 32 -> 16 ----
    {
        short8 Bh = FH[8 * 64 + lane];
        short8 Bl = FL[8 * 64 + lane];
        float bias5 = bsc[128 + nl];
        f32x4 a5[4];
#pragma unroll
        for (int t = 0; t < 4; ++t) {
            short8 Ah = *reinterpret_cast<const short8*>(&AH[aoff + t * 16 * RS]);
            short8 Al = *reinterpret_cast<const short8*>(&AL[aoff + t * 16 * RS]);
            f32x4 a = {bias5, bias5, bias5, bias5};
            a = __builtin_amdgcn_mfma_f32_16x16x32_bf16(Ah, Bh, a, 0, 0, 0);
            a = __builtin_amdgcn_mfma_f32_16x16x32_bf16(Ah, Bl, a, 0, 0, 0);
            a = __builtin_amdgcn_mfma_f32_16x16x32_bf16(Al, Bh, a, 0, 0, 0);
            a5[t] = a;
        }
        // h = sin(.), store hi/lo bf16 at [m][k=nl] (cols 0..15)
#pragma unroll
        for (int t = 0; t < 4; ++t)
#pragma unroll
            for (int r = 0; r < 4; ++r) {
                float s = sin_rev(a5[t][r]);
                unsigned short h, l2;
                bsplit(s, h, l2);
                const int m = 16 * t + 4 * q + r;
                AH[m * RS + nl] = h;
                AL[m * RS + nl] = l2;
            }
    }

    // ---- final: 16 -> 3 + sigmoid, point-per-lane readback ----
    {
        short8 H0 = *reinterpret_cast<const short8*>(&AH[lane * RS + 0]);
        short8 H1 = *reinterpret_cast<const short8*>(&AH[lane * RS + 8]);
        short8 L0v = *reinterpret_cast<const short8*>(&AL[lane * RS + 0]);
        short8 L1v = *reinterpret_cast<const short8*>(&AL[lane * RS + 8]);
        float hv[16];
#pragma unroll
        for (int k = 0; k < 8; ++k) {
            hv[k] = bf2f(H0[k]) + bf2f(L0v[k]);
            hv[k + 8] = bf2f(H1[k]) + bf2f(L1v[k]);
        }
        float o[3];
#pragma unroll
        for (int c = 0; c < 3; ++c) {
            float a = bfin[c];
#pragma unroll
            for (int k = 0; k < 16; ++k) a = fmaf(wf[c * 16 + k], hv[k], a);
            o[c] = fast_sigmoid(a);
        }
        if (pt < n) {
            out[pt * 3 + 0] = o[0];
            out[pt * 3 + 1] = o[1];
            out[pt * 3 + 2] = o[2];
        }
    }
}

extern "C" void kernel_launch(void* const* d_in, const int* in_sizes, int n_in,
                              void* d_out, int out_size, void* d_ws, size_t ws_size,
                              hipStream_t stream) {
    const float* coords = (const float*)d_in[0];
    const float* w0 = (const float*)d_in[1];
    const float* b0 = (const float*)d_in[2];
    const float* w1 = (const float*)d_in[3];
    const float* b1 = (const float*)d_in[4];
    const float* w2 = (const float*)d_in[5];
    const float* b2 = (const float*)d_in[6];
    const float* w3 = (const float*)d_in[7];
    const float* b3 = (const float*)d_in[8];
    const float* w4 = (const float*)d_in[9];
    const float* b4 = (const float*)d_in[10];
    const float* w5 = (const float*)d_in[11];
    const float* b5 = (const float*)d_in[12];
    const float* wf = (const float*)d_in[13];
    const float* bf = (const float*)d_in[14];
    float* out = (float*)d_out;

    // ws layout: frag_hi [0,9216), frag_lo [9216,18432), bsc [18432,19008)
    unsigned short* frag_hi = (unsigned short*)d_ws;
    unsigned short* frag_lo = (unsigned short*)((char*)d_ws + 9216);
    float* bsc = (float*)((char*)d_ws + 18432);

    const int n = in_sizes[0] / 2;

    prep_kernel<<<1, 64, 0, stream>>>(w1, w2, w3, w4, w5, b1, b2, b3, b4, b5,
                                      frag_hi, frag_lo, bsc);
    siren_mfma<<<(n + 255) / 256, 256, 0, stream>>>(
        coords, w0, b0, frag_hi, frag_lo, bsc, wf, bf, out, n);
}

// Round 3
// 181.172 us; speedup vs baseline: 2.2478x; 1.1725x over previous
//
#include <hip/hip_runtime.h>
#include <hip/hip_bf16.h>

// SIREN via MFMA, bf16 hi/lo split, packed-u32 LDS activations.
// Wave = 64 points. Layers 1..5 as v_mfma_f32_16x16x32_bf16, 3 products (hh+hl+lh).
// Split by TRUNCATION: hi = f & 0xffff0000, lo = f - hi (exact); lo's own trunc
// error ~2^-17 — hi+lo sum precision unchanged vs RNE, 3 VALU ops vs ~10.
// LDS element = u32 (hi16<<16 | lo16), row stride 36 u32 (144 B: 16B-aligned,
// bank-stride 4 -> 2-way conflicts = free). No fract: v_sin_f32 valid +-256 rev,
// inputs are <= ~3 rev. 30/(2pi) folded into all weights/biases by prep.

#define SINSCALE 4.774648292756860f   // 30/(2*pi)
#define RSU 36                         // act row stride in u32 (144 B)
#define SEL_HI 0x07060302u             // perm: D = [a.hi16, b.hi16]
#define SEL_LO 0x05040100u             // perm: D = [a.lo16, b.lo16]

typedef __attribute__((ext_vector_type(8))) short short8;
typedef __attribute__((ext_vector_type(4))) float f32x4;

union S8U { unsigned int u[4]; short8 s; };

__device__ __forceinline__ float fast_sigmoid(float t) {
    float e = __builtin_amdgcn_exp2f(t * -1.4426950408889634f);
    return 1.0f / (1.0f + e);
}

// pack sin-output f into (hi_bf16 << 16) | lo_bf16, truncation split
__device__ __forceinline__ unsigned int packsplit(float f) {
    unsigned int fb = __float_as_uint(f);
    unsigned int hib = fb & 0xffff0000u;
    float lo = f - __uint_as_float(hib);
    return __builtin_amdgcn_perm(fb, __float_as_uint(lo), SEL_HI);
}

union BFU { __hip_bfloat16 b; unsigned short u; };

__device__ __forceinline__ void bsplit_rne(float v, unsigned short& h, unsigned short& l) {
    BFU x; x.b = __float2bfloat16(v);           // RNE fine for prep (runs once)
    h = x.u;
    float fh = __uint_as_float(((unsigned)x.u) << 16);
    BFU y; y.b = __float2bfloat16(v - fh);
    l = y.u;
}

// ---- prep: B-frag hi/lo for w1..w5 (scaled), scaled biases, scaled w0/b0 ----
// 576 threads: s = tid>>6 in [0,9), lane = tid&63.
// B frag (16x16x32): lane L holds B[k=(L>>4)*8+j][n=(L&15)+16u] = W[n][k]*S.
__global__ void prep_kernel(const float* __restrict__ w1, const float* __restrict__ w2,
                            const float* __restrict__ w3, const float* __restrict__ w4,
                            const float* __restrict__ w5,
                            const float* __restrict__ b1, const float* __restrict__ b2,
                            const float* __restrict__ b3, const float* __restrict__ b4,
                            const float* __restrict__ b5,
                            const float* __restrict__ w0, const float* __restrict__ b0,
                            unsigned short* __restrict__ frag_hi,
                            unsigned short* __restrict__ frag_lo,
                            float* __restrict__ bsc,
                            float* __restrict__ w0s, float* __restrict__ b0s) {
    int tid = threadIdx.x;
    int s = tid >> 6, lane = tid & 63;
    const float* Ws[5] = {w1, w2, w3, w4, w5};
    const float* W = Ws[s >> 1];
    int u = s & 1;                       // s=8 -> u=0, W=w5
    int nrow = (lane & 15) + 16 * u;
    int k0 = (lane >> 4) * 8;
    for (int j = 0; j < 8; ++j) {
        float v = W[nrow * 32 + k0 + j] * SINSCALE;
        unsigned short h, l;
        bsplit_rne(v, h, l);
        frag_hi[(s * 64 + lane) * 8 + j] = h;
        frag_lo[(s * 64 + lane) * 8 + j] = l;
    }
    if (tid < 128) {
        const float* Bs[4] = {b1, b2, b3, b4};
        bsc[tid] = Bs[tid >> 5][tid & 31] * SINSCALE;
    } else if (tid < 144) {
        bsc[tid] = b5[tid - 128] * SINSCALE;
    } else if (tid < 208) {
        w0s[tid - 144] = w0[tid - 144] * SINSCALE;
    } else if (tid < 240) {
        b0s[tid - 208] = b0[tid - 208] * SINSCALE;
    }
}

__global__ __launch_bounds__(256, 4) void siren_mfma(
    const float* __restrict__ coords,
    const float* __restrict__ w0s, const float* __restrict__ b0s,
    const unsigned short* __restrict__ frag_hi,
    const unsigned short* __restrict__ frag_lo,
    const float* __restrict__ bsc,
    const float* __restrict__ wf, const float* __restrict__ bfin,
    float* __restrict__ out, int n) {
    __shared__ __align__(16) unsigned int lds[4][64 * RSU];  // 36864 B/block

    const int lane = (int)(threadIdx.x & 63);
    const int wv = (int)(threadIdx.x >> 6);
    unsigned int* A = &lds[wv][0];

    const int pbase = blockIdx.x * 256 + wv * 64;
    const int pt = pbase + lane;
    const int ptc = min(pt, n - 1);

    // ---- L0: 2 -> 32, point-per-lane; buffer 4 packed and ds_write_b128 ----
    {
        const float2 c = reinterpret_cast<const float2*>(coords)[ptc];
#pragma unroll
        for (int j0 = 0; j0 < 32; j0 += 4) {
            uint4 wb;
            unsigned int* wbp = &wb.x;
#pragma unroll
            for (int j = 0; j < 4; ++j) {
                float a = fmaf(w0s[2 * (j0 + j)], c.x,
                               fmaf(w0s[2 * (j0 + j) + 1], c.y, b0s[j0 + j]));
                wbp[j] = packsplit(__builtin_amdgcn_sinf(a));
            }
            *reinterpret_cast<uint4*>(&A[lane * RSU + j0]) = wb;
        }
    }

    const int q = lane >> 4;
    const int nl = lane & 15;

    const short8* FH = reinterpret_cast<const short8*>(frag_hi);
    const short8* FL = reinterpret_cast<const short8*>(frag_lo);

    // ---- middle layers 1..4: 32 -> 32 ----
#pragma unroll 1
    for (int l = 0; l < 4; ++l) {
        short8 Bh0 = FH[(l * 2 + 0) * 64 + lane];
        short8 Bh1 = FH[(l * 2 + 1) * 64 + lane];
        short8 Bl0 = FL[(l * 2 + 0) * 64 + lane];
        short8 Bl1 = FL[(l * 2 + 1) * 64 + lane];
        float bias0 = bsc[l * 32 + nl];
        float bias1 = bsc[l * 32 + nl + 16];

        f32x4 acc[4][2];
#pragma unroll
        for (int t = 0; t < 4; ++t) {
            const uint4* ar = reinterpret_cast<const uint4*>(&A[(16 * t + nl) * RSU + 8 * q]);
            uint4 p0 = ar[0];
            uint4 p1 = ar[1];
            S8U Ah, Al;
            Ah.u[0] = __builtin_amdgcn_perm(p0.y, p0.x, SEL_HI);
            Ah.u[1] = __builtin_amdgcn_perm(p0.w, p0.z, SEL_HI);
            Ah.u[2] = __builtin_amdgcn_perm(p1.y, p1.x, SEL_HI);
            Ah.u[3] = __builtin_amdgcn_perm(p1.w, p1.z, SEL_HI);
            Al.u[0] = __builtin_amdgcn_perm(p0.y, p0.x, SEL_LO);
            Al.u[1] = __builtin_amdgcn_perm(p0.w, p0.z, SEL_LO);
            Al.u[2] = __builtin_amdgcn_perm(p1.y, p1.x, SEL_LO);
            Al.u[3] = __builtin_amdgcn_perm(p1.w, p1.z, SEL_LO);
            f32x4 a0 = {bias0, bias0, bias0, bias0};
            a0 = __builtin_amdgcn_mfma_f32_16x16x32_bf16(Ah.s, Bh0, a0, 0, 0, 0);
            a0 = __builtin_amdgcn_mfma_f32_16x16x32_bf16(Ah.s, Bl0, a0, 0, 0, 0);
            a0 = __builtin_amdgcn_mfma_f32_16x16x32_bf16(Al.s, Bh0, a0, 0, 0, 0);
            f32x4 a1 = {bias1, bias1, bias1, bias1};
            a1 = __builtin_amdgcn_mfma_f32_16x16x32_bf16(Ah.s, Bh1, a1, 0, 0, 0);
            a1 = __builtin_amdgcn_mfma_f32_16x16x32_bf16(Ah.s, Bl1, a1, 0, 0, 0);
            a1 = __builtin_amdgcn_mfma_f32_16x16x32_bf16(Al.s, Bh1, a1, 0, 0, 0);
            acc[t][0] = a0;
            acc[t][1] = a1;
        }
        // activation + packed write back (C layout: row=16t+4q+r, col=nl+16u)
#pragma unroll
        for (int t = 0; t < 4; ++t)
#pragma unroll
            for (int u = 0; u < 2; ++u)
#pragma unroll
                for (int r = 0; r < 4; ++r) {
                    float s = __builtin_amdgcn_sinf(acc[t][u][r]);
                    const int m = 16 * t + 4 * q + r;
                    A[m * RSU + nl + 16 * u] = packsplit(s);
                }
    }

    // ---- L5: 32 -> 16; store raw f32 (no packing, consumed by VALU) ----
    {
        short8 Bh = FH[8 * 64 + lane];
        short8 Bl = FL[8 * 64 + lane];
        float bias5 = bsc[128 + nl];
        f32x4 a5[4];
#pragma unroll
        for (int t = 0; t < 4; ++t) {
            const uint4* ar = reinterpret_cast<const uint4*>(&A[(16 * t + nl) * RSU + 8 * q]);
            uint4 p0 = ar[0];
            uint4 p1 = ar[1];
            S8U Ah, Al;
            Ah.u[0] = __builtin_amdgcn_perm(p0.y, p0.x, SEL_HI);
            Ah.u[1] = __builtin_amdgcn_perm(p0.w, p0.z, SEL_HI);
            Ah.u[2] = __builtin_amdgcn_perm(p1.y, p1.x, SEL_HI);
            Ah.u[3] = __builtin_amdgcn_perm(p1.w, p1.z, SEL_HI);
            Al.u[0] = __builtin_amdgcn_perm(p0.y, p0.x, SEL_LO);
            Al.u[1] = __builtin_amdgcn_perm(p0.w, p0.z, SEL_LO);
            Al.u[2] = __builtin_amdgcn_perm(p1.y, p1.x, SEL_LO);
            Al.u[3] = __builtin_amdgcn_perm(p1.w, p1.z, SEL_LO);
            f32x4 a = {bias5, bias5, bias5, bias5};
            a = __builtin_amdgcn_mfma_f32_16x16x32_bf16(Ah.s, Bh, a, 0, 0, 0);
            a = __builtin_amdgcn_mfma_f32_16x16x32_bf16(Ah.s, Bl, a, 0, 0, 0);
            a = __builtin_amdgcn_mfma_f32_16x16x32_bf16(Al.s, Bh, a, 0, 0, 0);
            a5[t] = a;
        }
#pragma unroll
        for (int t = 0; t < 4; ++t)
#pragma unroll
            for (int r = 0; r < 4; ++r) {
                float s = __builtin_amdgcn_sinf(a5[t][r]);
                const int m = 16 * t + 4 * q + r;
                A[m * RSU + nl] = __float_as_uint(s);
            }
    }

    // ---- final: 16 -> 3 + sigmoid, point-per-lane f32 readback ----
    {
        float hv[16];
        const uint4* hr = reinterpret_cast<const uint4*>(&A[lane * RSU]);
#pragma unroll
        for (int cch = 0; cch < 4; ++cch) {
            uint4 v = hr[cch];
            hv[4 * cch + 0] = __uint_as_float(v.x);
            hv[4 * cch + 1] = __uint_as_float(v.y);
            hv[4 * cch + 2] = __uint_as_float(v.z);
            hv[4 * cch + 3] = __uint_as_float(v.w);
        }
        float o[3];
#pragma unroll
        for (int c = 0; c < 3; ++c) {
            float a = bfin[c];
#pragma unroll
            for (int k = 0; k < 16; ++k) a = fmaf(wf[c * 16 + k], hv[k], a);
            o[c] = fast_sigmoid(a);
        }
        if (pt < n) {
            out[pt * 3 + 0] = o[0];
            out[pt * 3 + 1] = o[1];
            out[pt * 3 + 2] = o[2];
        }
    }
}

extern "C" void kernel_launch(void* const* d_in, const int* in_sizes, int n_in,
                              void* d_out, int out_size, void* d_ws, size_t ws_size,
                              hipStream_t stream) {
    const float* coords = (const float*)d_in[0];
    const float* w0 = (const float*)d_in[1];
    const float* b0 = (const float*)d_in[2];
    const float* w1 = (const float*)d_in[3];
    const float* b1 = (const float*)d_in[4];
    const float* w2 = (const float*)d_in[5];
    const float* b2 = (const float*)d_in[6];
    const float* w3 = (const float*)d_in[7];
    const float* b3 = (const float*)d_in[8];
    const float* w4 = (const float*)d_in[9];
    const float* b4 = (const float*)d_in[10];
    const float* w5 = (const float*)d_in[11];
    const float* b5 = (const float*)d_in[12];
    const float* wf = (const float*)d_in[13];
    const float* bf = (const float*)d_in[14];
    float* out = (float*)d_out;

    // ws: frag_hi [0,9216) frag_lo [9216,18432) bsc(144f) [18432,19008)
    //     w0s(64f) [19008,19264) b0s(32f) [19264,19392)
    unsigned short* frag_hi = (unsigned short*)d_ws;
    unsigned short* frag_lo = (unsigned short*)((char*)d_ws + 9216);
    float* bsc = (float*)((char*)d_ws + 18432);
    float* w0s = (float*)((char*)d_ws + 19008);
    float* b0s = (float*)((char*)d_ws + 19264);

    const int n = in_sizes[0] / 2;

    prep_kernel<<<1, 576, 0, stream>>>(w1, w2, w3, w4, w5, b1, b2, b3, b4, b5,
                                       w0, b0, frag_hi, frag_lo, bsc, w0s, b0s);
    siren_mfma<<<(n + 255) / 256, 256, 0, stream>>>(
        coords, w0s, b0s, frag_hi, frag_lo, bsc, wf, bf, out, n);
}

// Round 4
// 161.833 us; speedup vs baseline: 2.5164x; 1.1195x over previous
//
#include <hip/hip_runtime.h>
#include <hip/hip_fp16.h>

// SIREN via MFMA fp16, interleaved-K hi/lo weights.
// Activations: one u32 per element = (f16(x) , f16(x)) duplicated halves.
// Weights: B'[2k][n]=hi(W[n][k]*S), B'[2k+1][n]=lo -> plain K=64 contraction
// (2x mfma_f32_16x16x32_f16) gives x_f16 * (hi+lo) = exact-weight product.
// A-operand reads packed LDS stream directly (ds_read_b128, ZERO unpack perms).
// C/D layout: col=lane&15, row=(lane>>4)*4+reg; A: m=lane&15, k=(lane>>4)*8+j.
// LDS row stride 36 dw (144B: 16B-aligned, write-scatter conflict-free).
// 30/(2pi) folded into weights/biases by prep; v_sin_f32 valid range +-256 rev.

#define SINSCALE 4.774648292756860f   // 30/(2*pi)
#define RSU 36                         // act row stride in u32

typedef __attribute__((ext_vector_type(8))) _Float16 half8;
typedef __attribute__((ext_vector_type(4))) float f32x4;

union S16 { uint4 u4; half8 h; };
union HU { __half h; unsigned short u; };

__device__ __forceinline__ float fast_sigmoid(float t) {
    float e = __builtin_amdgcn_exp2f(t * -1.4426950408889634f);
    return 1.0f / (1.0f + e);
}

// f32 -> u32 with f16(x) in BOTH halves: v_cvt_f16_f32 + v_perm (2 ops)
__device__ __forceinline__ unsigned int dupf16(float x) {
    HU hu; hu.h = __float2half(x);              // RNE, sits in low 16 bits
    unsigned int w = (unsigned int)hu.u;
    return __builtin_amdgcn_perm(w, w, 0x01000100u);  // [b1 b0 b1 b0]
}

// ---- prep: 19 blocks x 64. s<18: weight frags; s==18: biases + scaled w0/b0.
// frag s: s = l*4 + u*2 + half for l in [0,4) (w1..w4); s=16/17: w5 (u=0).
// lane holds B'[k'=(lane>>4)*8+j + 32*half][n=(lane&15)+16u], k=k'>>1,
// plane k'&1: 0 -> hi16(W*S), 1 -> lo16.
__global__ void prep_kernel(const float* __restrict__ w1, const float* __restrict__ w2,
                            const float* __restrict__ w3, const float* __restrict__ w4,
                            const float* __restrict__ w5,
                            const float* __restrict__ b1, const float* __restrict__ b2,
                            const float* __restrict__ b3, const float* __restrict__ b4,
                            const float* __restrict__ b5,
                            const float* __restrict__ w0, const float* __restrict__ b0,
                            unsigned short* __restrict__ frags,
                            float* __restrict__ bsc,
                            float* __restrict__ w0s, float* __restrict__ b0s) {
    int s = blockIdx.x, lane = threadIdx.x;
    if (s < 18) {
        const float* Ws[5] = {w1, w2, w3, w4, w5};
        const float* W = Ws[s < 16 ? (s >> 2) : 4];
        int u = (s < 16) ? ((s >> 1) & 1) : 0;
        int half = s & 1;
        int n = (lane & 15) + 16 * u;
        for (int j = 0; j < 8; ++j) {
            int kp = half * 32 + ((lane >> 4) << 3) + j;
            int k = kp >> 1;
            float v = W[n * 32 + k] * SINSCALE;
            HU hi; hi.h = __float2half(v);
            float h32 = __half2float(hi.h);
            HU outv;
            if (kp & 1) outv.h = __float2half(v - h32);
            else        outv = hi;
            frags[(s * 64 + lane) * 8 + j] = outv.u;
        }
    } else {
        const float* Bs[4] = {b1, b2, b3, b4};
        for (int i = lane; i < 128; i += 64) bsc[i] = Bs[i >> 5][i & 31] * SINSCALE;
        if (lane < 16) bsc[128 + lane] = b5[lane] * SINSCALE;
        w0s[lane] = w0[lane] * SINSCALE;
        if (lane < 32) b0s[lane] = b0[lane] * SINSCALE;
    }
}

__global__ __launch_bounds__(256, 4) void siren_mfma(
    const float* __restrict__ coords,
    const float* __restrict__ w0s, const float* __restrict__ b0s,
    const unsigned short* __restrict__ frags,
    const float* __restrict__ bsc,
    const float* __restrict__ wf, const float* __restrict__ bfin,
    float* __restrict__ out, int n) {
    __shared__ __align__(16) unsigned int lds[4][64 * RSU];  // 36864 B/block

    const int lane = (int)(threadIdx.x & 63);
    const int wv = (int)(threadIdx.x >> 6);
    unsigned int* A = &lds[wv][0];

    const int pt = blockIdx.x * 256 + wv * 64 + lane;
    const int ptc = min(pt, n - 1);

    // ---- L0: 2 -> 32, point-per-lane; 4 packed elements per ds_write_b128 ----
    {
        const float2 c = reinterpret_cast<const float2*>(coords)[ptc];
#pragma unroll
        for (int j0 = 0; j0 < 32; j0 += 4) {
            uint4 wb;
            unsigned int* wbp = &wb.x;
#pragma unroll
            for (int j = 0; j < 4; ++j) {
                float a = fmaf(w0s[2 * (j0 + j)], c.x,
                               fmaf(w0s[2 * (j0 + j) + 1], c.y, b0s[j0 + j]));
                wbp[j] = dupf16(__builtin_amdgcn_sinf(a));
            }
            *reinterpret_cast<uint4*>(&A[lane * RSU + j0]) = wb;
        }
    }

    const int q = lane >> 4;
    const int nl = lane & 15;

    const uint4* F = reinterpret_cast<const uint4*>(frags);

    // ---- middle layers 1..4: 32 -> 32, K'=64 over interleaved hi/lo weights ----
#pragma unroll 1
    for (int l = 0; l < 4; ++l) {
        S16 Bu0k0, Bu0k1, Bu1k0, Bu1k1;
        Bu0k0.u4 = F[(l * 4 + 0) * 64 + lane];
        Bu0k1.u4 = F[(l * 4 + 1) * 64 + lane];
        Bu1k0.u4 = F[(l * 4 + 2) * 64 + lane];
        Bu1k1.u4 = F[(l * 4 + 3) * 64 + lane];
        float bias0 = bsc[l * 32 + nl];
        float bias1 = bsc[l * 32 + nl + 16];

        f32x4 acc[4][2];
#pragma unroll
        for (int t = 0; t < 4; ++t) {
            const uint4* row = reinterpret_cast<const uint4*>(&A[(16 * t + nl) * RSU]);
            S16 a0, a1;
            a0.u4 = row[q];        // k' 0..31 portion for this lane
            a1.u4 = row[4 + q];    // k' 32..63
            f32x4 c0 = {bias0, bias0, bias0, bias0};
            c0 = __builtin_amdgcn_mfma_f32_16x16x32_f16(a0.h, Bu0k0.h, c0, 0, 0, 0);
            c0 = __builtin_amdgcn_mfma_f32_16x16x32_f16(a1.h, Bu0k1.h, c0, 0, 0, 0);
            f32x4 c1 = {bias1, bias1, bias1, bias1};
            c1 = __builtin_amdgcn_mfma_f32_16x16x32_f16(a0.h, Bu1k0.h, c1, 0, 0, 0);
            c1 = __builtin_amdgcn_mfma_f32_16x16x32_f16(a1.h, Bu1k1.h, c1, 0, 0, 0);
            acc[t][0] = c0;
            acc[t][1] = c1;
        }
        // activation + packed write back (C layout: row=16t+4q+r, col=nl+16u)
#pragma unroll
        for (int t = 0; t < 4; ++t)
#pragma unroll
            for (int u = 0; u < 2; ++u)
#pragma unroll
                for (int r = 0; r < 4; ++r) {
                    float s = __builtin_amdgcn_sinf(acc[t][u][r]);
                    const int m = 16 * t + 4 * q + r;
                    A[m * RSU + nl + 16 * u] = dupf16(s);
                }
    }

    // ---- L5: 32 -> 16; store raw f32 (consumed by VALU) ----
    {
        S16 B5k0, B5k1;
        B5k0.u4 = F[16 * 64 + lane];
        B5k1.u4 = F[17 * 64 + lane];
        float bias5 = bsc[128 + nl];
        f32x4 a5[4];
#pragma unroll
        for (int t = 0; t < 4; ++t) {
            const uint4* row = reinterpret_cast<const uint4*>(&A[(16 * t + nl) * RSU]);
            S16 a0, a1;
            a0.u4 = row[q];
            a1.u4 = row[4 + q];
            f32x4 c = {bias5, bias5, bias5, bias5};
            c = __builtin_amdgcn_mfma_f32_16x16x32_f16(a0.h, B5k0.h, c, 0, 0, 0);
            c = __builtin_amdgcn_mfma_f32_16x16x32_f16(a1.h, B5k1.h, c, 0, 0, 0);
            a5[t] = c;
        }
#pragma unroll
        for (int t = 0; t < 4; ++t)
#pragma unroll
            for (int r = 0; r < 4; ++r) {
                float s = __builtin_amdgcn_sinf(a5[t][r]);
                const int m = 16 * t + 4 * q + r;
                A[m * RSU + nl] = __float_as_uint(s);
            }
    }

    // ---- final: 16 -> 3 + sigmoid, point-per-lane f32 readback ----
    {
        float hv[16];
        const uint4* hr = reinterpret_cast<const uint4*>(&A[lane * RSU]);
#pragma unroll
        for (int cch = 0; cch < 4; ++cch) {
            uint4 v = hr[cch];
            hv[4 * cch + 0] = __uint_as_float(v.x);
            hv[4 * cch + 1] = __uint_as_float(v.y);
            hv[4 * cch + 2] = __uint_as_float(v.z);
            hv[4 * cch + 3] = __uint_as_float(v.w);
        }
        float o[3];
#pragma unroll
        for (int c = 0; c < 3; ++c) {
            float a = bfin[c];
#pragma unroll
            for (int k = 0; k < 16; ++k) a = fmaf(wf[c * 16 + k], hv[k], a);
            o[c] = fast_sigmoid(a);
        }
        if (pt < n) {
            out[pt * 3 + 0] = o[0];
            out[pt * 3 + 1] = o[1];
            out[pt * 3 + 2] = o[2];
        }
    }
}

extern "C" void kernel_launch(void* const* d_in, const int* in_sizes, int n_in,
                              void* d_out, int out_size, void* d_ws, size_t ws_size,
                              hipStream_t stream) {
    const float* coords = (const float*)d_in[0];
    const float* w0 = (const float*)d_in[1];
    const float* b0 = (const float*)d_in[2];
    const float* w1 = (const float*)d_in[3];
    const float* b1 = (const float*)d_in[4];
    const float* w2 = (const float*)d_in[5];
    const float* b2 = (const float*)d_in[6];
    const float* w3 = (const float*)d_in[7];
    const float* b3 = (const float*)d_in[8];
    const float* w4 = (const float*)d_in[9];
    const float* b4 = (const float*)d_in[10];
    const float* w5 = (const float*)d_in[11];
    const float* b5 = (const float*)d_in[12];
    const float* wf = (const float*)d_in[13];
    const float* bf = (const float*)d_in[14];
    float* out = (float*)d_out;

    // ws: frags 18*64*8 f16 = 18432 B [0,18432); bsc(144f) [18432,19008);
    //     w0s(64f) [19008,19264); b0s(32f) [19264,19392)
    unsigned short* frags = (unsigned short*)d_ws;
    float* bsc = (float*)((char*)d_ws + 18432);
    float* w0s = (float*)((char*)d_ws + 19008);
    float* b0s = (float*)((char*)d_ws + 19264);

    const int n = in_sizes[0] / 2;

    prep_kernel<<<19, 64, 0, stream>>>(w1, w2, w3, w4, w5, b1, b2, b3, b4, b5,
                                       w0, b0, frags, bsc, w0s, b0s);
    siren_mfma<<<(n + 255) / 256, 256, 0, stream>>>(
        coords, w0s, b0s, frags, bsc, wf, bf, out, n);
}

// Round 6
// 146.852 us; speedup vs baseline: 2.7731x; 1.1020x over previous
//
#include <hip/hip_runtime.h>
#include <hip/hip_fp16.h>

// SIREN via MFMA f16, A=weights / B=activations orientation.
// D[16 feat x 16 pt] = W[16 feat x 32 in] * X[32 in x 16 pt].
// C/D: col=lane&15 -> point, row=(lane>>4)*4+reg -> feature (consecutive per lane!)
// -> activations pack pairwise with ONE v_cvt_pkrtz per 2 elems, stored as plain
// f16 stream that IS the next layer's B-fragment k-order (ds_read_b128, no perms).
// Weight precision: hi/lo f16 split as TWO A-fragments, two chained MFMAs per tile
// (x_f16 * (hi+lo) = exact-weight product; only activation f16 quant remains).
// LDS: row per point, 32 f16 = 16 dw + 4 pad = 20 dw stride (2-way conflicts, free).
// 5 KB/wave, 20 KB/block -> 6+ blocks/CU. 30/(2pi) folded into weights/biases.

#define SINSCALE 4.774648292756860f   // 30/(2*pi)
#define RSD 20                         // act row stride in dwords

typedef __attribute__((ext_vector_type(8))) _Float16 half8;
typedef __attribute__((ext_vector_type(2))) __fp16 fp16x2;
typedef __attribute__((ext_vector_type(4))) float f32x4;

union S16 { uint4 u4; half8 h; };
union PK { fp16x2 h2; unsigned int u; };
union HU { __half h; unsigned short u; };

__device__ __forceinline__ float fast_sigmoid(float t) {
    float e = __builtin_amdgcn_exp2f(t * -1.4426950408889634f);
    return 1.0f / (1.0f + e);
}

// pack two f32 -> one u32 of two f16 (RTZ), 1 instruction
__device__ __forceinline__ unsigned int pk2(float a, float b) {
    PK p; p.h2 = __builtin_amdgcn_cvt_pkrtz(a, b);
    return p.u;
}

// ---- prep: 19 blocks x 64 lanes ----
// A-frag (16x16x32 f16): lane holds A[m=lane&15][k=(lane>>4)*8+j], j=0..7.
// frag s<16: l=s>>2 (w1..w4), u=(s>>1)&1 (feature tile), h=s&1 (0=hi,1=lo):
//   value = split(W[l][16u+m][k] * SINSCALE).  s=16+h: w5 (u=0).
// s==18 block: scaled biases bsc[0..144), scaled w0 (64), b0 (32).
__global__ void prep_kernel(const float* __restrict__ w1, const float* __restrict__ w2,
                            const float* __restrict__ w3, const float* __restrict__ w4,
                            const float* __restrict__ w5,
                            const float* __restrict__ b1, const float* __restrict__ b2,
                            const float* __restrict__ b3, const float* __restrict__ b4,
                            const float* __restrict__ b5,
                            const float* __restrict__ w0, const float* __restrict__ b0,
                            unsigned short* __restrict__ frags,
                            float* __restrict__ bsc,
                            float* __restrict__ w0s, float* __restrict__ b0s) {
    int s = blockIdx.x, lane = threadIdx.x;
    if (s < 18) {
        const float* Ws[5] = {w1, w2, w3, w4, w5};
        const float* W = Ws[s < 16 ? (s >> 2) : 4];
        int u = (s < 16) ? ((s >> 1) & 1) : 0;
        int hsel = s & 1;
        int m = (lane & 15) + 16 * u;
        int k0 = (lane >> 4) << 3;
        for (int j = 0; j < 8; ++j) {
            float v = W[m * 32 + k0 + j] * SINSCALE;
            HU hi; hi.h = __float2half(v);           // RNE
            HU outv;
            if (hsel) outv.h = __float2half(v - __half2float(hi.h));
            else      outv = hi;
            frags[(s * 64 + lane) * 8 + j] = outv.u;
        }
    } else {
        const float* Bs[4] = {b1, b2, b3, b4};
        for (int i = lane; i < 128; i += 64) bsc[i] = Bs[i >> 5][i & 31] * SINSCALE;
        if (lane < 16) bsc[128 + lane] = b5[lane] * SINSCALE;
        w0s[lane] = w0[lane] * SINSCALE;
        if (lane < 32) b0s[lane] = b0[lane] * SINSCALE;
    }
}

__global__ __launch_bounds__(256, 6) void siren_mfma(
    const float* __restrict__ coords,
    const float* __restrict__ w0s, const float* __restrict__ b0s,
    const unsigned short* __restrict__ frags,
    const float* __restrict__ bsc,
    const float* __restrict__ wf, const float* __restrict__ bfin,
    float* __restrict__ out, int n) {
    __shared__ __align__(16) unsigned int lds[4][64 * RSD];  // 20480 B/block

    const int lane = (int)(threadIdx.x & 63);
    const int wv = (int)(threadIdx.x >> 6);
    unsigned int* A = &lds[wv][0];

    const int pt = blockIdx.x * 256 + wv * 64 + lane;
    const int ptc = min(pt, n - 1);

    const int q = lane >> 4;
    const int nl = lane & 15;

    // ---- L0: 2 -> 32, point-per-lane; rows = own point, f16-pair packed ----
    {
        const float2 c = reinterpret_cast<const float2*>(coords)[ptc];
#pragma unroll
        for (int j0 = 0; j0 < 32; j0 += 8) {
            float s[8];
#pragma unroll
            for (int j = 0; j < 8; ++j) {
                float a = fmaf(w0s[2 * (j0 + j)], c.x,
                               fmaf(w0s[2 * (j0 + j) + 1], c.y, b0s[j0 + j]));
                s[j] = __builtin_amdgcn_sinf(a);
            }
            uint4 wb;
            wb.x = pk2(s[0], s[1]);
            wb.y = pk2(s[2], s[3]);
            wb.z = pk2(s[4], s[5]);
            wb.w = pk2(s[6], s[7]);
            *reinterpret_cast<uint4*>(&A[lane * RSD + j0 / 2]) = wb;
        }
    }

    const uint4* F = reinterpret_cast<const uint4*>(frags);

    // ---- middle layers 1..4: 32 -> 32 ----
#pragma unroll 1
    for (int l = 0; l < 4; ++l) {
        S16 Ah0, Al0, Ah1, Al1;
        Ah0.u4 = F[(l * 4 + 0) * 64 + lane];
        Al0.u4 = F[(l * 4 + 1) * 64 + lane];
        Ah1.u4 = F[(l * 4 + 2) * 64 + lane];
        Al1.u4 = F[(l * 4 + 3) * 64 + lane];
        const float4 bq0 = *reinterpret_cast<const float4*>(&bsc[l * 32 + 4 * q]);
        const float4 bq1 = *reinterpret_cast<const float4*>(&bsc[l * 32 + 16 + 4 * q]);
        const f32x4 bv0 = {bq0.x, bq0.y, bq0.z, bq0.w};
        const f32x4 bv1 = {bq1.x, bq1.y, bq1.z, bq1.w};

        f32x4 acc[4][2];
#pragma unroll
        for (int t = 0; t < 4; ++t) {
            S16 Bt;
            Bt.u4 = *reinterpret_cast<const uint4*>(&A[(16 * t + nl) * RSD + 4 * q]);
            f32x4 c0 = __builtin_amdgcn_mfma_f32_16x16x32_f16(Ah0.h, Bt.h, bv0, 0, 0, 0);
            c0 = __builtin_amdgcn_mfma_f32_16x16x32_f16(Al0.h, Bt.h, c0, 0, 0, 0);
            f32x4 c1 = __builtin_amdgcn_mfma_f32_16x16x32_f16(Ah1.h, Bt.h, bv1, 0, 0, 0);
            c1 = __builtin_amdgcn_mfma_f32_16x16x32_f16(Al1.h, Bt.h, c1, 0, 0, 0);
            acc[t][0] = c0;
            acc[t][1] = c1;
        }
        // activation + pairwise pack; lane's outputs: point 16t+nl, feats 16u+4q+r
#pragma unroll
        for (int t = 0; t < 4; ++t)
#pragma unroll
            for (int u = 0; u < 2; ++u) {
                float s0 = __builtin_amdgcn_sinf(acc[t][u][0]);
                float s1 = __builtin_amdgcn_sinf(acc[t][u][1]);
                float s2 = __builtin_amdgcn_sinf(acc[t][u][2]);
                float s3 = __builtin_amdgcn_sinf(acc[t][u][3]);
                uint2 wb;
                wb.x = pk2(s0, s1);
                wb.y = pk2(s2, s3);
                *reinterpret_cast<uint2*>(&A[(16 * t + nl) * RSD + 8 * u + 2 * q]) = wb;
            }
    }

    // ---- L5: 32 -> 16; outputs stored as raw f32 (consumed by VALU) ----
    {
        S16 Ah5, Al5;
        Ah5.u4 = F[16 * 64 + lane];
        Al5.u4 = F[17 * 64 + lane];
        const float4 bq5 = *reinterpret_cast<const float4*>(&bsc[128 + 4 * q]);
        const f32x4 bv5 = {bq5.x, bq5.y, bq5.z, bq5.w};
        f32x4 a5[4];
#pragma unroll
        for (int t = 0; t < 4; ++t) {
            S16 Bt;
            Bt.u4 = *reinterpret_cast<const uint4*>(&A[(16 * t + nl) * RSD + 4 * q]);
            f32x4 c = __builtin_amdgcn_mfma_f32_16x16x32_f16(Ah5.h, Bt.h, bv5, 0, 0, 0);
            c = __builtin_amdgcn_mfma_f32_16x16x32_f16(Al5.h, Bt.h, c, 0, 0, 0);
            a5[t] = c;
        }
#pragma unroll
        for (int t = 0; t < 4; ++t) {
            uint4 wb;
            wb.x = __float_as_uint(__builtin_amdgcn_sinf(a5[t][0]));
            wb.y = __float_as_uint(__builtin_amdgcn_sinf(a5[t][1]));
            wb.z = __float_as_uint(__builtin_amdgcn_sinf(a5[t][2]));
            wb.w = __float_as_uint(__builtin_amdgcn_sinf(a5[t][3]));
            *reinterpret_cast<uint4*>(&A[(16 * t + nl) * RSD + 4 * q]) = wb;
        }
    }

    // ---- final: 16 -> 3 + sigmoid, point-per-lane f32 readback ----
    {
        float hv[16];
        const uint4* hr = reinterpret_cast<const uint4*>(&A[lane * RSD]);
#pragma unroll
        for (int cch = 0; cch < 4; ++cch) {
            uint4 v = hr[cch];
            hv[4 * cch + 0] = __uint_as_float(v.x);
            hv[4 * cch + 1] = __uint_as_float(v.y);
            hv[4 * cch + 2] = __uint_as_float(v.z);
            hv[4 * cch + 3] = __uint_as_float(v.w);
        }
        float o[3];
#pragma unroll
        for (int c = 0; c < 3; ++c) {
            float a = bfin[c];
#pragma unroll
            for (int k = 0; k < 16; ++k) a = fmaf(wf[c * 16 + k], hv[k], a);
            o[c] = fast_sigmoid(a);
        }
        if (pt < n) {
            out[pt * 3 + 0] = o[0];
            out[pt * 3 + 1] = o[1];
            out[pt * 3 + 2] = o[2];
        }
    }
}

extern "C" void kernel_launch(void* const* d_in, const int* in_sizes, int n_in,
                              void* d_out, int out_size, void* d_ws, size_t ws_size,
                              hipStream_t stream) {
    const float* coords = (const float*)d_in[0];
    const float* w0 = (const float*)d_in[1];
    const float* b0 = (const float*)d_in[2];
    const float* w1 = (const float*)d_in[3];
    const float* b1 = (const float*)d_in[4];
    const float* w2 = (const float*)d_in[5];
    const float* b2 = (const float*)d_in[6];
    const float* w3 = (const float*)d_in[7];
    const float* b3 = (const float*)d_in[8];
    const float* w4 = (const float*)d_in[9];
    const float* b4 = (const float*)d_in[10];
    const float* w5 = (const float*)d_in[11];
    const float* b5 = (const float*)d_in[12];
    const float* wf = (const float*)d_in[13];
    const float* bf = (const float*)d_in[14];
    float* out = (float*)d_out;

    // ws: frags 18*64*8 f16 = 18432 B [0,18432); bsc(144f) [18432,19008);
    //     w0s(64f) [19008,19264); b0s(32f) [19264,19392)
    unsigned short* frags = (unsigned short*)d_ws;
    float* bsc = (float*)((char*)d_ws + 18432);
    float* w0s = (float*)((char*)d_ws + 19008);
    float* b0s = (float*)((char*)d_ws + 19264);

    const int n = in_sizes[0] / 2;

    prep_kernel<<<19, 64, 0, stream>>>(w1, w2, w3, w4, w5, b1, b2, b3, b4, b5,
                                       w0, b0, frags, bsc, w0s, b0s);
    siren_mfma<<<(n + 255) / 256, 256, 0, stream>>>(
        coords, w0s, b0s, frags, bsc, wf, bf, out, n);
}